// Round 6
// baseline (638.985 us; speedup 1.0000x reference)
//
#include <hip/hip_runtime.h>
#include <math.h>

#define CC 96
#define BB 512
#define TT 512

// ---------------------------------------------------------------------------
// Kernel 0: column max of transitions and E[i][j] = exp(T[i][j]-maxT[j])
// ---------------------------------------------------------------------------
__global__ __launch_bounds__(128) void crf_prep(const float* __restrict__ trans,
                                                float* __restrict__ E,
                                                float* __restrict__ maxT) {
    int j = threadIdx.x;
    if (j < CC) {
        float m = -INFINITY;
        for (int i = 0; i < CC; ++i) m = fmaxf(m, trans[i * CC + j]);
        maxT[j] = m;
        for (int i = 0; i < CC; ++i) E[i * CC + j] = __expf(trans[i * CC + j] - m);
    }
}

// ---------------------------------------------------------------------------
// Kernel 1: forward recurrence, linear space, ONE WAVE per batch chain.
// Round-5 lesson: per-step latency 1880cy, ~1280 of it the LDS round-trip +
// 2-wave barrier. This version has NO LDS and NO barriers in the hot loop:
// lane l owns states (2l, 2l+1); the p-vector broadcast is v_readlane
// (constant lane, VALU pipe, uniform result) feeding v_fmac with an SGPR
// operand. Chain latency collapses to ~VALU issue time.
// E pair-columns pinned in 192 VGPRs (asm, rounds 2-4 lesson);
// __launch_bounds__(64,1) for the full register budget.
// Renorm every 8 steps via shfl_xor (all lanes get identical sum).
// Inactive lanes (l>=48): mT=-inf => scale=0 => p stays exactly 0.
// ---------------------------------------------------------------------------
__global__ __launch_bounds__(64, 1) void crf_forward(const float* __restrict__ emissions,
                                                     const int* __restrict__ mask,
                                                     const float* __restrict__ start_t,
                                                     const float* __restrict__ end_t,
                                                     const float* __restrict__ E,
                                                     const float* __restrict__ maxT,
                                                     float* __restrict__ log_den) {
    const int b = blockIdx.x;
    const int l = threadIdx.x;          // 0..63
    const bool act = (l < 48);
    const int lc = act ? l : 47;        // clamped pair index
    const int s0 = 2 * lc;              // this lane's states: s0, s0+1

    // E columns (s0, s0+1) for all i -> 192 VGPRs, pinned.
    float ex[CC], ey[CC];
#pragma unroll
    for (int i = 0; i < CC; ++i) {
        const float2 e = *(const float2*)(E + i * CC + s0);
        ex[i] = e.x; ey[i] = e.y;
        asm volatile("" : "+v"(ex[i]), "+v"(ey[i]));
    }

    const size_t bbase = (size_t)b * TT * CC;
    float mTx = maxT[s0], mTy = maxT[s0 + 1];
    if (!act) { mTx = -INFINITY; mTy = -INFINITY; }   // forces sc=0 -> p stays 0

    // --- init t=0: p = exp(start + em0) (no shift needed; renorm@8 bounds it) ---
    float px = 0.f, py = 0.f;
    {
        const float2 em0 = *(const float2*)(emissions + bbase + s0);
        if (act) {
            px = __expf(start_t[s0]     + em0.x);
            py = __expf(start_t[s0 + 1] + em0.y);
        }
    }
    double S = 0.0;

    // emission/mask prefetch slots for t = 1..4 (4-step vmcnt window)
    float emx[4], emy[4];
    int   mks[4];
#pragma unroll
    for (int s = 0; s < 4; ++s) {
        const float2 e = *(const float2*)(emissions + bbase + (size_t)(1 + s) * CC + s0);
        emx[s] = e.x; emy[s] = e.y;
        mks[s] = mask[b * TT + 1 + s];
    }

    auto STEP = [&](float cex, float cey, int cmk, bool dorenorm) {
        const float scx = __expf(mTx + cex);        // off-chain (em loaded 4 steps ago)
        const float scy = __expf(mTy + cey);

        // broadcast-matvec: q[j] = sum_i p[i] * E[i][j], i distributed 2/lane
        float qx[4] = {0.f, 0.f, 0.f, 0.f};
        float qy[4] = {0.f, 0.f, 0.f, 0.f};
#pragma unroll
        for (int m = 0; m < 48; ++m) {
            const float pxm = __int_as_float(__builtin_amdgcn_readlane(__float_as_int(px), m));
            const float pym = __int_as_float(__builtin_amdgcn_readlane(__float_as_int(py), m));
            const int i0 = 2 * m, i1 = 2 * m + 1;
            qx[i0 & 3] = fmaf(pxm, ex[i0], qx[i0 & 3]);
            qy[i0 & 3] = fmaf(pxm, ey[i0], qy[i0 & 3]);
            qx[i1 & 3] = fmaf(pym, ex[i1], qx[i1 & 3]);
            qy[i1 & 3] = fmaf(pym, ey[i1], qy[i1 & 3]);
        }
        const float qxs = (qx[0] + qx[1]) + (qx[2] + qx[3]);
        const float qys = (qy[0] + qy[1]) + (qy[2] + qy[3]);

        if (cmk) { px = qxs * scx; py = qys * scy; }

        if (dorenorm) {
            float r = px + py;                       // inactive lanes contribute 0
#pragma unroll
            for (int off = 32; off; off >>= 1) r += __shfl_xor(r, off);
            const float inv = __builtin_amdgcn_rcpf(r);
            px *= inv; py *= inv;
            S += (double)__logf(r);
        }
    };

    // main loop: t = 1..508 in chunks of 4; tail 509..511.
    for (int tb = 1; tb + 3 < TT; tb += 4) {
#pragma unroll
        for (int s = 0; s < 4; ++s) {
            const int t = tb + s;
            const float cex = emx[s], cey = emy[s];
            const int   cmk = mks[s];
            const int   tn = t + 4;
            if (tn < TT) {                           // uniform guard
                const float2 e = *(const float2*)(emissions + bbase + (size_t)tn * CC + s0);
                emx[s] = e.x; emy[s] = e.y;
                mks[s] = mask[b * TT + tn];
            }
            STEP(cex, cey, cmk, (t & 7) == 0);
        }
    }
    STEP(emx[0], emy[0], mks[0], false);             // t = 509
    STEP(emx[1], emy[1], mks[1], false);             // t = 510
    STEP(emx[2], emy[2], mks[2], false);             // t = 511

    // --- final: log_den = S + log(sum_j p[j] * exp(end[j])) ---
    float fr = act ? (px * __expf(end_t[s0]) + py * __expf(end_t[s0 + 1])) : 0.f;
#pragma unroll
    for (int off = 32; off; off >>= 1) fr += __shfl_xor(fr, off);
    if (l == 0) log_den[b] = (float)(S + (double)__logf(fr));
}

// ---------------------------------------------------------------------------
// Kernel 2: joint likelihood (numerator) — one block per batch.
// ---------------------------------------------------------------------------
__global__ __launch_bounds__(256) void crf_joint(const float* __restrict__ emissions,
                                                 const int* __restrict__ tags,
                                                 const int* __restrict__ mask,
                                                 const float* __restrict__ trans,
                                                 const float* __restrict__ start_t,
                                                 const float* __restrict__ end_t,
                                                 float* __restrict__ log_num) {
    const int b = blockIdx.x;
    const int tid = threadIdx.x;
    float s = 0.f;
    int mcount = 0;
    for (int t = tid; t < TT; t += 256) {
        int tg = tags[b * TT + t];
        float em = emissions[((size_t)b * TT + t) * CC + tg];
        int mk = mask[b * TT + t];
        mcount += mk;
        if (t == 0) {
            s += start_t[tg] + em;  // t=0 term unmasked in reference
        } else {
            int tp = tags[b * TT + t - 1];
            s += mk ? (trans[tp * CC + tg] + em) : 0.f;
        }
    }
    __shared__ float sred[4];
    __shared__ int mred[4];
#pragma unroll
    for (int off = 32; off; off >>= 1) {
        s += __shfl_xor(s, off);
        mcount += __shfl_xor(mcount, off);
    }
    if ((tid & 63) == 0) { sred[tid >> 6] = s; mred[tid >> 6] = mcount; }
    __syncthreads();
    if (tid == 0) {
        float tot = (sred[0] + sred[1]) + (sred[2] + sred[3]);
        int mt = (mred[0] + mred[1]) + (mred[2] + mred[3]);
        int last_tag = tags[b * TT + (mt - 1)];
        log_num[b] = tot + end_t[last_tag];
    }
}

// ---------------------------------------------------------------------------
// Kernel 3: final mean(log_den - log_num)
// ---------------------------------------------------------------------------
__global__ __launch_bounds__(512) void crf_final(const float* __restrict__ log_den,
                                                 const float* __restrict__ log_num,
                                                 float* __restrict__ out) {
    const int tid = threadIdx.x;
    float d = log_den[tid] - log_num[tid];
#pragma unroll
    for (int off = 32; off; off >>= 1) d += __shfl_xor(d, off);
    __shared__ float sred[8];
    if ((tid & 63) == 0) sred[tid >> 6] = d;
    __syncthreads();
    if (tid == 0) {
        float tot = 0.f;
        for (int w = 0; w < 8; ++w) tot += sred[w];
        out[0] = tot / (float)BB;
    }
}

extern "C" void kernel_launch(void* const* d_in, const int* in_sizes, int n_in,
                              void* d_out, int out_size, void* d_ws, size_t ws_size,
                              hipStream_t stream) {
    const float* emissions = (const float*)d_in[0];
    const int*   tags      = (const int*)d_in[1];
    const int*   mask      = (const int*)d_in[2];
    const float* trans     = (const float*)d_in[3];
    const float* start_t   = (const float*)d_in[4];
    const float* end_t     = (const float*)d_in[5];
    float* out = (float*)d_out;

    float* ws      = (float*)d_ws;
    float* E       = ws;             // 9216 floats
    float* maxT    = ws + 9216;      // 96
    float* log_den = ws + 9312;      // 512
    float* log_num = ws + 9824;      // 512

    crf_prep<<<1, 128, 0, stream>>>(trans, E, maxT);
    crf_forward<<<BB, 64, 0, stream>>>(emissions, mask, start_t, end_t, E, maxT, log_den);
    crf_joint<<<BB, 256, 0, stream>>>(emissions, tags, mask, trans, start_t, end_t, log_num);
    crf_final<<<1, 512, 0, stream>>>(log_den, log_num, out);
}

// Round 8
// 344.948 us; speedup vs baseline: 1.8524x; 1.8524x over previous
//
#include <hip/hip_runtime.h>
#include <math.h>

#define CC 96
#define BB 512
#define TT 512

// ---------------------------------------------------------------------------
// Kernel 0: column max of transitions and E[i][j] = exp(T[i][j]-maxT[j])
// ---------------------------------------------------------------------------
__global__ __launch_bounds__(128) void crf_prep(const float* __restrict__ trans,
                                                float* __restrict__ E,
                                                float* __restrict__ maxT) {
    int j = threadIdx.x;
    if (j < CC) {
        float m = -INFINITY;
        for (int i = 0; i < CC; ++i) m = fmaxf(m, trans[i * CC + j]);
        maxT[j] = m;
        for (int i = 0; i < CC; ++i) E[i * CC + j] = __expf(trans[i * CC + j] - m);
    }
}

// ---------------------------------------------------------------------------
// Kernel 0b: pack mask rows into bit-words so the forward hot loop has ZERO
// scalar/SMEM loads (r5 lesson: uniform mask[] loads become s_load -> lgkm,
// and the per-step lgkmcnt(0) drained their L2 latency every step).
// ---------------------------------------------------------------------------
__global__ __launch_bounds__(64) void pack_mask(const int* __restrict__ mask,
                                                unsigned* __restrict__ mbits) {
    const int b = blockIdx.x;
    const int w = threadIdx.x;
    if (w < 16) {
        unsigned bits = 0u;
        for (int k = 0; k < 32; ++k)
            bits |= (mask[b * TT + w * 32 + k] ? 1u : 0u) << k;
        mbits[b * 16 + w] = bits;
    }
}

// ---------------------------------------------------------------------------
// Kernel 1: forward recurrence, linear space, ONE WAVE per chain, NO barriers,
// NO readlane (r6 lesson: VALU->SALU hazards + AGPR parking = 3030 cyc/step).
// Lane l owns states (2l,2l+1), l<48. Broadcast via within-wave LDS:
// ds_write_b64 -> lgkmcnt(0) -> 24x broadcast ds_read_b128. The matvec is
// explicit v_fmac_f32 inline asm with "v" operands so ex/ey MUST be VGPR-
// resident at every use (AGPR parking would cost 192 accvgpr_reads/step).
// Emissions prefetched 4 steps ahead; mask from packed bits; renorm every 8
// steps via shfl_xor. Inactive lanes: mT=-inf => scale 0 => p stays 0.
// ---------------------------------------------------------------------------
#define STEP(PF_, K_, BIT_, REN_) do {                                        \
    const int sl_ = (K_) & 3;                                                 \
    const int par_ = (K_) & 1;                                                \
    const float cex_ = es[sl_].x, cey_ = es[sl_].y;                           \
    es[sl_] = *(const float2*)(PF_);                                          \
    const float scx_ = __expf(mTx + cex_);                                    \
    const float scy_ = __expf(mTy + cey_);                                    \
    if (act) *(float2*)(&pl[par_][s0]) = make_float2(px, py);                 \
    asm volatile("s_waitcnt lgkmcnt(0)" ::: "memory");                        \
    float qx0=0.f,qx1=0.f,qx2=0.f,qx3=0.f;                                    \
    float qy0=0.f,qy1=0.f,qy2=0.f,qy3=0.f;                                    \
    _Pragma("unroll")                                                         \
    for (int i_ = 0; i_ < CC; i_ += 4) {                                      \
        const float4 v_ = *(const float4*)(&pl[par_][i_]);                    \
        asm("v_fmac_f32 %0, %2, %3\n\tv_fmac_f32 %1, %2, %4"                  \
            : "+v"(qx0), "+v"(qy0)                                            \
            : "v"(v_.x), "v"(ex[i_]), "v"(ey[i_]));                           \
        asm("v_fmac_f32 %0, %2, %3\n\tv_fmac_f32 %1, %2, %4"                  \
            : "+v"(qx1), "+v"(qy1)                                            \
            : "v"(v_.y), "v"(ex[i_+1]), "v"(ey[i_+1]));                       \
        asm("v_fmac_f32 %0, %2, %3\n\tv_fmac_f32 %1, %2, %4"                  \
            : "+v"(qx2), "+v"(qy2)                                            \
            : "v"(v_.z), "v"(ex[i_+2]), "v"(ey[i_+2]));                       \
        asm("v_fmac_f32 %0, %2, %3\n\tv_fmac_f32 %1, %2, %4"                  \
            : "+v"(qx3), "+v"(qy3)                                            \
            : "v"(v_.w), "v"(ex[i_+3]), "v"(ey[i_+3]));                       \
    }                                                                         \
    const float qx_ = (qx0+qx1)+(qx2+qx3);                                    \
    const float qy_ = (qy0+qy1)+(qy2+qy3);                                    \
    if (BIT_) { px = qx_ * scx_; py = qy_ * scy_; }                           \
    if (REN_) {                                                               \
        float r_ = px + py;                                                   \
        _Pragma("unroll")                                                     \
        for (int o_ = 32; o_; o_ >>= 1) r_ += __shfl_xor(r_, o_);             \
        const float inv_ = 1.0f / r_;                                         \
        px *= inv_; py *= inv_;                                               \
        S += (double)__logf(r_);                                              \
    }                                                                         \
} while (0)

__global__ __launch_bounds__(64, 1) void crf_forward(const float* __restrict__ emissions,
                                                     const unsigned* __restrict__ mbits,
                                                     const float* __restrict__ start_t,
                                                     const float* __restrict__ end_t,
                                                     const float* __restrict__ E,
                                                     const float* __restrict__ maxT,
                                                     float* __restrict__ log_den) {
    const int b = blockIdx.x;
    const int l = threadIdx.x;            // 0..63
    const bool act = (l < 48);
    const int lc = act ? l : 47;
    const int s0 = 2 * lc;                // this lane's states

    __shared__ __align__(16) float pl[2][CC];

    // E pair-columns -> 192 VGPRs (uses below are asm "v" operands)
    float ex[CC], ey[CC];
#pragma unroll
    for (int i = 0; i < CC; ++i) {
        const float2 e = *(const float2*)(E + i * CC + s0);
        ex[i] = e.x; ey[i] = e.y;
    }

    const float* ep = emissions + (size_t)b * TT * CC + s0;
    const float mTx = act ? maxT[s0]     : -INFINITY;
    const float mTy = act ? maxT[s0 + 1] : -INFINITY;

    // init t=0: p = exp(start + em0); renorm@8 keeps it bounded (< e^56 peak)
    float px = 0.f, py = 0.f;
    {
        const float2 e0 = *(const float2*)ep;
        if (act) {
            px = __expf(start_t[s0]     + e0.x);
            py = __expf(start_t[s0 + 1] + e0.y);
        }
    }
    double S = 0.0;

    // prefetch slots, es[t&3] holds emission(t), t = 1..4
    float2 es[4];
#pragma unroll
    for (int s = 1; s <= 4; ++s) es[s & 3] = *(const float2*)(ep + (size_t)s * CC);

    const float* pf = ep + (size_t)5 * CC;   // next prefetch target: t=5

    // head: t = 1..7 (word 0, no renorm)
    const unsigned wb0 = mbits[b * 16];
#pragma unroll
    for (int k = 1; k < 8; ++k) {
        STEP(pf, k, (wb0 >> k) & 1u, 0);
        pf += CC;
    }
    // main: sb = 1..62  (t = 8*sb + k); mask word prefetched one sb ahead
    unsigned swc = mbits[b * 16] >> 8;       // bits for t = 8..15
    for (int sb = 1; sb < 63; ++sb) {
        const int sbn = sb + 1;
        const unsigned swn = mbits[b * 16 + (sbn >> 2)] >> ((sbn & 3) * 8);
#pragma unroll
        for (int k = 0; k < 8; ++k) {
            STEP(pf, k, (swc >> k) & 1u, k == 0);
            pf += CC;
        }
        swc = swn;
    }
    // tail: t = 504..511, prefetch address clamped to t=511 (no OOB on b=511)
#pragma unroll
    for (int k = 0; k < 8; ++k) {
        const int t_ = 504 + k;
        const int tn_ = (t_ + 4 <= TT - 1) ? (t_ + 4) : (TT - 1);
        STEP(ep + (size_t)tn_ * CC, k, (swc >> k) & 1u, k == 0);
    }

    // final: log_den = S + log(sum_j p[j] * exp(end[j]))
    float fr = px * __expf(end_t[s0]) + py * __expf(end_t[s0 + 1]);  // inactive: 0
#pragma unroll
    for (int off = 32; off; off >>= 1) fr += __shfl_xor(fr, off);
    if (l == 0) log_den[b] = (float)(S + (double)__logf(fr));
}

// ---------------------------------------------------------------------------
// Kernel 2: joint likelihood (numerator) — one block per batch.
// ---------------------------------------------------------------------------
__global__ __launch_bounds__(256) void crf_joint(const float* __restrict__ emissions,
                                                 const int* __restrict__ tags,
                                                 const int* __restrict__ mask,
                                                 const float* __restrict__ trans,
                                                 const float* __restrict__ start_t,
                                                 const float* __restrict__ end_t,
                                                 float* __restrict__ log_num) {
    const int b = blockIdx.x;
    const int tid = threadIdx.x;
    float s = 0.f;
    int mcount = 0;
    for (int t = tid; t < TT; t += 256) {
        int tg = tags[b * TT + t];
        float em = emissions[((size_t)b * TT + t) * CC + tg];
        int mk = mask[b * TT + t];
        mcount += mk;
        if (t == 0) {
            s += start_t[tg] + em;  // t=0 term unmasked in reference
        } else {
            int tp = tags[b * TT + t - 1];
            s += mk ? (trans[tp * CC + tg] + em) : 0.f;
        }
    }
    __shared__ float sred[4];
    __shared__ int mred[4];
#pragma unroll
    for (int off = 32; off; off >>= 1) {
        s += __shfl_xor(s, off);
        mcount += __shfl_xor(mcount, off);
    }
    if ((tid & 63) == 0) { sred[tid >> 6] = s; mred[tid >> 6] = mcount; }
    __syncthreads();
    if (tid == 0) {
        float tot = (sred[0] + sred[1]) + (sred[2] + sred[3]);
        int mt = (mred[0] + mred[1]) + (mred[2] + mred[3]);
        int last_tag = tags[b * TT + (mt - 1)];
        log_num[b] = tot + end_t[last_tag];
    }
}

// ---------------------------------------------------------------------------
// Kernel 3: final mean(log_den - log_num)
// ---------------------------------------------------------------------------
__global__ __launch_bounds__(512) void crf_final(const float* __restrict__ log_den,
                                                 const float* __restrict__ log_num,
                                                 float* __restrict__ out) {
    const int tid = threadIdx.x;
    float d = log_den[tid] - log_num[tid];
#pragma unroll
    for (int off = 32; off; off >>= 1) d += __shfl_xor(d, off);
    __shared__ float sred[8];
    if ((tid & 63) == 0) sred[tid >> 6] = d;
    __syncthreads();
    if (tid == 0) {
        float tot = 0.f;
        for (int w = 0; w < 8; ++w) tot += sred[w];
        out[0] = tot / (float)BB;
    }
}

extern "C" void kernel_launch(void* const* d_in, const int* in_sizes, int n_in,
                              void* d_out, int out_size, void* d_ws, size_t ws_size,
                              hipStream_t stream) {
    const float* emissions = (const float*)d_in[0];
    const int*   tags      = (const int*)d_in[1];
    const int*   mask      = (const int*)d_in[2];
    const float* trans     = (const float*)d_in[3];
    const float* start_t   = (const float*)d_in[4];
    const float* end_t     = (const float*)d_in[5];
    float* out = (float*)d_out;

    float*    ws      = (float*)d_ws;
    float*    E       = ws;               // 9216 floats
    float*    maxT    = ws + 9216;        // 96
    float*    log_den = ws + 9312;        // 512
    float*    log_num = ws + 9824;        // 512
    unsigned* mbits   = (unsigned*)(ws + 10336);  // 512*16 u32

    crf_prep<<<1, 128, 0, stream>>>(trans, E, maxT);
    pack_mask<<<BB, 64, 0, stream>>>(mask, mbits);
    crf_forward<<<BB, 64, 0, stream>>>(emissions, mbits, start_t, end_t, E, maxT, log_den);
    crf_joint<<<BB, 256, 0, stream>>>(emissions, tags, mask, trans, start_t, end_t, log_num);
    crf_final<<<1, 512, 0, stream>>>(log_den, log_num, out);
}

// Round 10
// 343.019 us; speedup vs baseline: 1.8628x; 1.0056x over previous
//
#include <hip/hip_runtime.h>
#include <math.h>

#define CC 96
#define BB 512
#define TT 512

// ---------------------------------------------------------------------------
// Kernel 0: column max of transitions and E[i][j] = exp(T[i][j]-maxT[j])
// ---------------------------------------------------------------------------
__global__ __launch_bounds__(128) void crf_prep(const float* __restrict__ trans,
                                                float* __restrict__ E,
                                                float* __restrict__ maxT) {
    int j = threadIdx.x;
    if (j < CC) {
        float m = -INFINITY;
        for (int i = 0; i < CC; ++i) m = fmaxf(m, trans[i * CC + j]);
        maxT[j] = m;
        for (int i = 0; i < CC; ++i) E[i * CC + j] = __expf(trans[i * CC + j] - m);
    }
}

// ---------------------------------------------------------------------------
// Kernel 0b: pack mask rows into bit-words so the forward hot loop has ZERO
// scalar/SMEM loads (r5 lesson: uniform mask[] loads become s_load -> lgkm,
// and the per-step lgkmcnt(0) drained their L2 latency every step).
// ---------------------------------------------------------------------------
__global__ __launch_bounds__(64) void pack_mask(const int* __restrict__ mask,
                                                unsigned* __restrict__ mbits) {
    const int b = blockIdx.x;
    const int w = threadIdx.x;
    if (w < 16) {
        unsigned bits = 0u;
        for (int k = 0; k < 32; ++k)
            bits |= (mask[b * TT + w * 32 + k] ? 1u : 0u) << k;
        mbits[b * 16 + w] = bits;
    }
}

// ---------------------------------------------------------------------------
// Kernel 1: forward recurrence, linear space, ONE WAVE per chain, NO barriers.
// r8 lesson: VGPR_Count=128 -> the 192 E-values were still NOT VGPR-resident
// (AGPR-parked with per-use copies / remat), because __launch_bounds__(64,1)
// only CONSTRAINS occupancy (>=1 wave/EU legal) — it doesn't change the
// allocator's economizing TARGET. amdgpu_waves_per_eu(1,1) (max=1) removes
// any occupancy incentive: the allocator may freely use ~320 unified regs.
// Everything else identical to r8: LDS broadcast of p (ds_write_b64 ->
// lgkmcnt(0) -> 24x broadcast ds_read_b128), matvec as explicit v_fmac_f32
// asm with "v" operands, packed mask bits, emissions prefetched 4 steps
// ahead, renorm every 8 steps via shfl_xor.
// ---------------------------------------------------------------------------
#define STEP(PF_, K_, BIT_, REN_) do {                                        \
    const int sl_ = (K_) & 3;                                                 \
    const int par_ = (K_) & 1;                                                \
    const float cex_ = es[sl_].x, cey_ = es[sl_].y;                           \
    es[sl_] = *(const float2*)(PF_);                                          \
    const float scx_ = __expf(mTx + cex_);                                    \
    const float scy_ = __expf(mTy + cey_);                                    \
    if (act) *(float2*)(&pl[par_][s0]) = make_float2(px, py);                 \
    asm volatile("s_waitcnt lgkmcnt(0)" ::: "memory");                        \
    float qx0=0.f,qx1=0.f,qx2=0.f,qx3=0.f;                                    \
    float qy0=0.f,qy1=0.f,qy2=0.f,qy3=0.f;                                    \
    _Pragma("unroll")                                                         \
    for (int i_ = 0; i_ < CC; i_ += 4) {                                      \
        const float4 v_ = *(const float4*)(&pl[par_][i_]);                    \
        asm("v_fmac_f32 %0, %2, %3\n\tv_fmac_f32 %1, %2, %4"                  \
            : "+v"(qx0), "+v"(qy0)                                            \
            : "v"(v_.x), "v"(ex[i_]), "v"(ey[i_]));                           \
        asm("v_fmac_f32 %0, %2, %3\n\tv_fmac_f32 %1, %2, %4"                  \
            : "+v"(qx1), "+v"(qy1)                                            \
            : "v"(v_.y), "v"(ex[i_+1]), "v"(ey[i_+1]));                       \
        asm("v_fmac_f32 %0, %2, %3\n\tv_fmac_f32 %1, %2, %4"                  \
            : "+v"(qx2), "+v"(qy2)                                            \
            : "v"(v_.z), "v"(ex[i_+2]), "v"(ey[i_+2]));                       \
        asm("v_fmac_f32 %0, %2, %3\n\tv_fmac_f32 %1, %2, %4"                  \
            : "+v"(qx3), "+v"(qy3)                                            \
            : "v"(v_.w), "v"(ex[i_+3]), "v"(ey[i_+3]));                       \
    }                                                                         \
    const float qx_ = (qx0+qx1)+(qx2+qx3);                                    \
    const float qy_ = (qy0+qy1)+(qy2+qy3);                                    \
    if (BIT_) { px = qx_ * scx_; py = qy_ * scy_; }                           \
    if (REN_) {                                                               \
        float r_ = px + py;                                                   \
        _Pragma("unroll")                                                     \
        for (int o_ = 32; o_; o_ >>= 1) r_ += __shfl_xor(r_, o_);             \
        const float inv_ = 1.0f / r_;                                         \
        px *= inv_; py *= inv_;                                               \
        S += (double)__logf(r_);                                              \
    }                                                                         \
} while (0)

__global__ __launch_bounds__(64, 1)
__attribute__((amdgpu_waves_per_eu(1, 1)))
void crf_forward(const float* __restrict__ emissions,
                 const unsigned* __restrict__ mbits,
                 const float* __restrict__ start_t,
                 const float* __restrict__ end_t,
                 const float* __restrict__ E,
                 const float* __restrict__ maxT,
                 float* __restrict__ log_den) {
    const int b = blockIdx.x;
    const int l = threadIdx.x;            // 0..63
    const bool act = (l < 48);
    const int lc = act ? l : 47;
    const int s0 = 2 * lc;                // this lane's states

    __shared__ __align__(16) float pl[2][CC];

    // E pair-columns -> 192 VGPRs (uses below are asm "v" operands)
    float ex[CC], ey[CC];
#pragma unroll
    for (int i = 0; i < CC; ++i) {
        const float2 e = *(const float2*)(E + i * CC + s0);
        ex[i] = e.x; ey[i] = e.y;
    }

    const float* ep = emissions + (size_t)b * TT * CC + s0;
    const float mTx = act ? maxT[s0]     : -INFINITY;
    const float mTy = act ? maxT[s0 + 1] : -INFINITY;

    // init t=0: p = exp(start + em0); renorm@8 keeps it bounded (< e^56 peak)
    float px = 0.f, py = 0.f;
    {
        const float2 e0 = *(const float2*)ep;
        if (act) {
            px = __expf(start_t[s0]     + e0.x);
            py = __expf(start_t[s0 + 1] + e0.y);
        }
    }
    double S = 0.0;

    // prefetch slots, es[t&3] holds emission(t), t = 1..4
    float2 es[4];
#pragma unroll
    for (int s = 1; s <= 4; ++s) es[s & 3] = *(const float2*)(ep + (size_t)s * CC);

    const float* pf = ep + (size_t)5 * CC;   // next prefetch target: t=5

    // head: t = 1..7 (word 0, no renorm)
    const unsigned wb0 = mbits[b * 16];
#pragma unroll
    for (int k = 1; k < 8; ++k) {
        STEP(pf, k, (wb0 >> k) & 1u, 0);
        pf += CC;
    }
    // main: sb = 1..62  (t = 8*sb + k); mask word prefetched one sb ahead
    unsigned swc = mbits[b * 16] >> 8;       // bits for t = 8..15
    for (int sb = 1; sb < 63; ++sb) {
        const int sbn = sb + 1;
        const unsigned swn = mbits[b * 16 + (sbn >> 2)] >> ((sbn & 3) * 8);
#pragma unroll
        for (int k = 0; k < 8; ++k) {
            STEP(pf, k, (swc >> k) & 1u, k == 0);
            pf += CC;
        }
        swc = swn;
    }
    // tail: t = 504..511, prefetch address clamped to t=511 (no OOB on b=511)
#pragma unroll
    for (int k = 0; k < 8; ++k) {
        const int t_ = 504 + k;
        const int tn_ = (t_ + 4 <= TT - 1) ? (t_ + 4) : (TT - 1);
        STEP(ep + (size_t)tn_ * CC, k, (swc >> k) & 1u, k == 0);
    }

    // final: log_den = S + log(sum_j p[j] * exp(end[j]))
    float fr = px * __expf(end_t[s0]) + py * __expf(end_t[s0 + 1]);  // inactive: 0
#pragma unroll
    for (int off = 32; off; off >>= 1) fr += __shfl_xor(fr, off);
    if (l == 0) log_den[b] = (float)(S + (double)__logf(fr));
}

// ---------------------------------------------------------------------------
// Kernel 2: joint likelihood (numerator) — one block per batch.
// ---------------------------------------------------------------------------
__global__ __launch_bounds__(256) void crf_joint(const float* __restrict__ emissions,
                                                 const int* __restrict__ tags,
                                                 const int* __restrict__ mask,
                                                 const float* __restrict__ trans,
                                                 const float* __restrict__ start_t,
                                                 const float* __restrict__ end_t,
                                                 float* __restrict__ log_num) {
    const int b = blockIdx.x;
    const int tid = threadIdx.x;
    float s = 0.f;
    int mcount = 0;
    for (int t = tid; t < TT; t += 256) {
        int tg = tags[b * TT + t];
        float em = emissions[((size_t)b * TT + t) * CC + tg];
        int mk = mask[b * TT + t];
        mcount += mk;
        if (t == 0) {
            s += start_t[tg] + em;  // t=0 term unmasked in reference
        } else {
            int tp = tags[b * TT + t - 1];
            s += mk ? (trans[tp * CC + tg] + em) : 0.f;
        }
    }
    __shared__ float sred[4];
    __shared__ int mred[4];
#pragma unroll
    for (int off = 32; off; off >>= 1) {
        s += __shfl_xor(s, off);
        mcount += __shfl_xor(mcount, off);
    }
    if ((tid & 63) == 0) { sred[tid >> 6] = s; mred[tid >> 6] = mcount; }
    __syncthreads();
    if (tid == 0) {
        float tot = (sred[0] + sred[1]) + (sred[2] + sred[3]);
        int mt = (mred[0] + mred[1]) + (mred[2] + mred[3]);
        int last_tag = tags[b * TT + (mt - 1)];
        log_num[b] = tot + end_t[last_tag];
    }
}

// ---------------------------------------------------------------------------
// Kernel 3: final mean(log_den - log_num)
// ---------------------------------------------------------------------------
__global__ __launch_bounds__(512) void crf_final(const float* __restrict__ log_den,
                                                 const float* __restrict__ log_num,
                                                 float* __restrict__ out) {
    const int tid = threadIdx.x;
    float d = log_den[tid] - log_num[tid];
#pragma unroll
    for (int off = 32; off; off >>= 1) d += __shfl_xor(d, off);
    __shared__ float sred[8];
    if ((tid & 63) == 0) sred[tid >> 6] = d;
    __syncthreads();
    if (tid == 0) {
        float tot = 0.f;
        for (int w = 0; w < 8; ++w) tot += sred[w];
        out[0] = tot / (float)BB;
    }
}

extern "C" void kernel_launch(void* const* d_in, const int* in_sizes, int n_in,
                              void* d_out, int out_size, void* d_ws, size_t ws_size,
                              hipStream_t stream) {
    const float* emissions = (const float*)d_in[0];
    const int*   tags      = (const int*)d_in[1];
    const int*   mask      = (const int*)d_in[2];
    const float* trans     = (const float*)d_in[3];
    const float* start_t   = (const float*)d_in[4];
    const float* end_t     = (const float*)d_in[5];
    float* out = (float*)d_out;

    float*    ws      = (float*)d_ws;
    float*    E       = ws;               // 9216 floats
    float*    maxT    = ws + 9216;        // 96
    float*    log_den = ws + 9312;        // 512
    float*    log_num = ws + 9824;        // 512
    unsigned* mbits   = (unsigned*)(ws + 10336);  // 512*16 u32

    crf_prep<<<1, 128, 0, stream>>>(trans, E, maxT);
    pack_mask<<<BB, 64, 0, stream>>>(mask, mbits);
    crf_forward<<<BB, 64, 0, stream>>>(emissions, mbits, start_t, end_t, E, maxT, log_den);
    crf_joint<<<BB, 256, 0, stream>>>(emissions, tags, mask, trans, start_t, end_t, log_num);
    crf_final<<<1, 512, 0, stream>>>(log_den, log_num, out);
}

// Round 11
// 249.387 us; speedup vs baseline: 2.5622x; 1.3754x over previous
//
#include <hip/hip_runtime.h>
#include <math.h>

#define CC 96
#define BB 512
#define TT 512

// ---------------------------------------------------------------------------
// Kernel 0: column max of transitions and E[i][j] = exp(T[i][j]-maxT[j])
// ---------------------------------------------------------------------------
__global__ __launch_bounds__(128) void crf_prep(const float* __restrict__ trans,
                                                float* __restrict__ E,
                                                float* __restrict__ maxT) {
    int j = threadIdx.x;
    if (j < CC) {
        float m = -INFINITY;
        for (int i = 0; i < CC; ++i) m = fmaxf(m, trans[i * CC + j]);
        maxT[j] = m;
        for (int i = 0; i < CC; ++i) E[i * CC + j] = __expf(trans[i * CC + j] - m);
    }
}

// ---------------------------------------------------------------------------
// Kernel 0b: pack mask rows into bit-words (no SMEM loads in the hot loop).
// ---------------------------------------------------------------------------
__global__ __launch_bounds__(64) void pack_mask(const int* __restrict__ mask,
                                                unsigned* __restrict__ mbits) {
    const int b = blockIdx.x;
    const int w = threadIdx.x;
    if (w < 16) {
        unsigned bits = 0u;
        for (int k = 0; k < 32; ++k)
            bits |= (mask[b * TT + w * 32 + k] ? 1u : 0u) << k;
        mbits[b * 16 + w] = bits;
    }
}

// ---------------------------------------------------------------------------
// Kernel 1: forward recurrence, linear space, TWO waves per chain, i-SPLIT.
// r10 lesson: the allocator will NOT give one wave >128 arch VGPRs (3 failed
// escalations); 192 E-values/wave => ~192 AGPR-copy insts/step. Redesign to
// FIT: wave w owns E rows 48w..48w+47 as 48 float2 (96 VGPRs). Lane l owns
// output pair j=(2l,2l+1). Per step, per wave:
//   24x ds_read_b64 of own p-half (broadcast) + 48x v_pk_fma_f32 (op_sel
//   broadcasts the p scalar from a 64-bit pair) -> partial[j-pair]
//   -> write partial -> lgkmcnt(0)+s_barrier (ONE barrier, no vmcnt drain)
//   -> read other wave's partial -> q = mine+other -> p_new = q*exp(mT+em)
//   -> each wave writes its own i-half of p_new to its PRIVATE parity buffer
//      (same-wave DS ordering => no second barrier).
// p_new is computed REPLICATED in both waves (identical values).
// Emissions prefetched 4 steps ahead (counted vmcnt); packed mask bits;
// renorm every 8 steps via shfl (identical in both waves).
// ---------------------------------------------------------------------------
#define PKFMA_LO(A_, S_, E_) \
    asm("v_pk_fma_f32 %0, %1, %2, %0 op_sel:[0,0,0] op_sel_hi:[0,1,1]" \
        : "+v"(A_) : "v"(S_), "v"(E_))
#define PKFMA_HI(A_, S_, E_) \
    asm("v_pk_fma_f32 %0, %1, %2, %0 op_sel:[1,0,0] op_sel_hi:[1,1,1]" \
        : "+v"(A_) : "v"(S_), "v"(E_))

#define STEP(PF_, K_, BIT_, REN_) do {                                        \
    const int sl_ = (K_) & 3;                                                 \
    const int pr_ = (K_) & 1;                                                 \
    const float cex_ = es[sl_].x, cey_ = es[sl_].y;                           \
    es[sl_] = *(const float2*)(PF_);                                          \
    const float scx_ = __expf(mTx + cex_);                                    \
    const float scy_ = __expf(mTy + cey_);                                    \
    float2 a0 = {0.f,0.f}, a1 = {0.f,0.f}, a2 = {0.f,0.f}, a3 = {0.f,0.f};    \
    _Pragma("unroll")                                                         \
    for (int i_ = 0; i_ < 48; i_ += 4) {                                      \
        const float2 pA_ = *(const float2*)&pb[w][pr_][i_];                   \
        const float2 pB_ = *(const float2*)&pb[w][pr_][i_ + 2];               \
        PKFMA_LO(a0, pA_, ep2[i_]);                                           \
        PKFMA_HI(a1, pA_, ep2[i_ + 1]);                                       \
        PKFMA_LO(a2, pB_, ep2[i_ + 2]);                                       \
        PKFMA_HI(a3, pB_, ep2[i_ + 3]);                                       \
    }                                                                         \
    float2 mine_;                                                             \
    mine_.x = (a0.x + a1.x) + (a2.x + a3.x);                                  \
    mine_.y = (a0.y + a1.y) + (a2.y + a3.y);                                  \
    if (act) *(float2*)&pex[w][pr_][2 * l] = mine_;                           \
    asm volatile("s_waitcnt lgkmcnt(0)" ::: "memory");                        \
    __builtin_amdgcn_s_barrier();                                             \
    const float2 oth_ = *(const float2*)&pex[1 - w][pr_][2 * l];              \
    const float qx_ = mine_.x + oth_.x;                                       \
    const float qy_ = mine_.y + oth_.y;                                       \
    if (BIT_) { px = qx_ * scx_; py = qy_ * scy_; }                           \
    if (REN_) {                                                               \
        float r_ = px + py;                                                   \
        _Pragma("unroll")                                                     \
        for (int o_ = 32; o_; o_ >>= 1) r_ += __shfl_xor(r_, o_);             \
        const float inv_ = 1.0f / r_;                                         \
        px *= inv_; py *= inv_;                                               \
        S += (double)__logf(r_);                                              \
    }                                                                         \
    if (l >= wlo && l < whi)                                                  \
        *(float2*)&pb[w][pr_ ^ 1][2 * l - 48 * w] = make_float2(px, py);      \
} while (0)

__global__ __launch_bounds__(128, 1)
void crf_forward(const float* __restrict__ emissions,
                 const unsigned* __restrict__ mbits,
                 const float* __restrict__ start_t,
                 const float* __restrict__ end_t,
                 const float* __restrict__ E,
                 const float* __restrict__ maxT,
                 float* __restrict__ log_den) {
    const int b = blockIdx.x;
    const int w = threadIdx.x >> 6;       // wave 0/1: owns i-rows 48w..48w+47
    const int l = threadIdx.x & 63;       // lane: owns output pair (2l, 2l+1)
    const bool act = (l < 48);
    const int lc = act ? l : 47;
    const int s0 = 2 * lc;
    const int wlo = 24 * w, whi = 24 * w + 24;   // lanes that write own p-half

    __shared__ __align__(16) float pb[2][2][48];   // [wave][parity][i-local]
    __shared__ __align__(16) float pex[2][2][CC];  // partial exchange

    // E rows (48w + i) at columns (s0, s0+1) -> 48 float2 = 96 VGPRs
    float2 ep2[48];
#pragma unroll
    for (int i = 0; i < 48; ++i)
        ep2[i] = *(const float2*)(E + (size_t)(48 * w + i) * CC + s0);

    const float* ep = emissions + (size_t)b * TT * CC + s0;
    const float mTx = act ? maxT[s0]     : -INFINITY;
    const float mTy = act ? maxT[s0 + 1] : -INFINITY;

    // init t=0: p = exp(start + em0), replicated in both waves
    float px = 0.f, py = 0.f;
    {
        const float2 e0 = *(const float2*)ep;
        if (act) {
            px = __expf(start_t[s0]     + e0.x);
            py = __expf(start_t[s0 + 1] + e0.y);
        }
    }
    double S = 0.0;
    if (l >= wlo && l < whi)
        *(float2*)&pb[w][1][2 * l - 48 * w] = make_float2(px, py);

    // emission prefetch slots: es[t&3] holds emission(t), t=1..4
    float2 es[4];
#pragma unroll
    for (int s = 1; s <= 4; ++s) es[s & 3] = *(const float2*)(ep + (size_t)s * CC);
    const float* pf = ep + (size_t)5 * CC;

    // head: t = 1..7
    const unsigned wb0 = mbits[b * 16];
#pragma unroll
    for (int k = 1; k < 8; ++k) {
        STEP(pf, k, (wb0 >> k) & 1u, 0);
        pf += CC;
    }
    // main: sb = 1..62 (t = 8*sb + k)
    unsigned swc = mbits[b * 16] >> 8;
    for (int sb = 1; sb < 63; ++sb) {
        const int sbn = sb + 1;
        const unsigned swn = mbits[b * 16 + (sbn >> 2)] >> ((sbn & 3) * 8);
#pragma unroll
        for (int k = 0; k < 8; ++k) {
            STEP(pf, k, (swc >> k) & 1u, k == 0);
            pf += CC;
        }
        swc = swn;
    }
    // tail: t = 504..511, prefetch clamped to t=511
#pragma unroll
    for (int k = 0; k < 8; ++k) {
        const int t_ = 504 + k;
        const int tn_ = (t_ + 4 <= TT - 1) ? (t_ + 4) : (TT - 1);
        STEP(ep + (size_t)tn_ * CC, k, (swc >> k) & 1u, k == 0);
    }

    // final: log_den = S + log(sum_j p[j] * exp(end[j]))  (all lanes have own pair)
    float fr = act ? (px * __expf(end_t[s0]) + py * __expf(end_t[s0 + 1])) : 0.f;
#pragma unroll
    for (int off = 32; off; off >>= 1) fr += __shfl_xor(fr, off);
    if (threadIdx.x == 0) log_den[b] = (float)(S + (double)__logf(fr));
}

// ---------------------------------------------------------------------------
// Kernel 2: joint likelihood (numerator) — one block per batch.
// ---------------------------------------------------------------------------
__global__ __launch_bounds__(256) void crf_joint(const float* __restrict__ emissions,
                                                 const int* __restrict__ tags,
                                                 const int* __restrict__ mask,
                                                 const float* __restrict__ trans,
                                                 const float* __restrict__ start_t,
                                                 const float* __restrict__ end_t,
                                                 float* __restrict__ log_num) {
    const int b = blockIdx.x;
    const int tid = threadIdx.x;
    float s = 0.f;
    int mcount = 0;
    for (int t = tid; t < TT; t += 256) {
        int tg = tags[b * TT + t];
        float em = emissions[((size_t)b * TT + t) * CC + tg];
        int mk = mask[b * TT + t];
        mcount += mk;
        if (t == 0) {
            s += start_t[tg] + em;  // t=0 term unmasked in reference
        } else {
            int tp = tags[b * TT + t - 1];
            s += mk ? (trans[tp * CC + tg] + em) : 0.f;
        }
    }
    __shared__ float sred[4];
    __shared__ int mred[4];
#pragma unroll
    for (int off = 32; off; off >>= 1) {
        s += __shfl_xor(s, off);
        mcount += __shfl_xor(mcount, off);
    }
    if ((tid & 63) == 0) { sred[tid >> 6] = s; mred[tid >> 6] = mcount; }
    __syncthreads();
    if (tid == 0) {
        float tot = (sred[0] + sred[1]) + (sred[2] + sred[3]);
        int mt = (mred[0] + mred[1]) + (mred[2] + mred[3]);
        int last_tag = tags[b * TT + (mt - 1)];
        log_num[b] = tot + end_t[last_tag];
    }
}

// ---------------------------------------------------------------------------
// Kernel 3: final mean(log_den - log_num)
// ---------------------------------------------------------------------------
__global__ __launch_bounds__(512) void crf_final(const float* __restrict__ log_den,
                                                 const float* __restrict__ log_num,
                                                 float* __restrict__ out) {
    const int tid = threadIdx.x;
    float d = log_den[tid] - log_num[tid];
#pragma unroll
    for (int off = 32; off; off >>= 1) d += __shfl_xor(d, off);
    __shared__ float sred[8];
    if ((tid & 63) == 0) sred[tid >> 6] = d;
    __syncthreads();
    if (tid == 0) {
        float tot = 0.f;
        for (int w = 0; w < 8; ++w) tot += sred[w];
        out[0] = tot / (float)BB;
    }
}

extern "C" void kernel_launch(void* const* d_in, const int* in_sizes, int n_in,
                              void* d_out, int out_size, void* d_ws, size_t ws_size,
                              hipStream_t stream) {
    const float* emissions = (const float*)d_in[0];
    const int*   tags      = (const int*)d_in[1];
    const int*   mask      = (const int*)d_in[2];
    const float* trans     = (const float*)d_in[3];
    const float* start_t   = (const float*)d_in[4];
    const float* end_t     = (const float*)d_in[5];
    float* out = (float*)d_out;

    float*    ws      = (float*)d_ws;
    float*    E       = ws;               // 9216 floats
    float*    maxT    = ws + 9216;        // 96
    float*    log_den = ws + 9312;        // 512
    float*    log_num = ws + 9824;        // 512
    unsigned* mbits   = (unsigned*)(ws + 10336);  // 512*16 u32

    crf_prep<<<1, 128, 0, stream>>>(trans, E, maxT);
    pack_mask<<<BB, 64, 0, stream>>>(mask, mbits);
    crf_forward<<<BB, 128, 0, stream>>>(emissions, mbits, start_t, end_t, E, maxT, log_den);
    crf_joint<<<BB, 256, 0, stream>>>(emissions, tags, mask, trans, start_t, end_t, log_num);
    crf_final<<<1, 512, 0, stream>>>(log_den, log_num, out);
}